// Round 1
// baseline (330.766 us; speedup 1.0000x reference)
//
#include <hip/hip_runtime.h>
#include <hip/hip_bf16.h>

// Problem: Bahdanau attention. B=32, T=2048, D=512, U=512.
// d_in: values[B,T,D] f32, query[B,D] f32, W1_w[D,U], W1_b[U], W2_w[D,U],
//       W2_b[U], V_w[U,1], V_b[1]
// d_out: context[B,D] (16384 f32) then attention_weights[B,T,1] (65536 f32)

#define B_DIM 32
#define T_DIM 2048
#define D_DIM 512
#define U_DIM 512
#define M_DIM (B_DIM * T_DIM)   // 65536 rows

typedef short bf16x8 __attribute__((ext_vector_type(8)));
typedef float f32x4 __attribute__((ext_vector_type(4)));

// round-to-nearest-even f32 -> bf16 (bit trick, no header dependence)
__device__ __forceinline__ short bf16r(float x) {
    unsigned u = __float_as_uint(x);
    u += 0x7fffu + ((u >> 16) & 1u);
    return (short)(u >> 16);
}

__device__ __forceinline__ bf16x8 pack_bf16x8(float4 a, float4 b) {
    bf16x8 r;
    r[0] = bf16r(a.x); r[1] = bf16r(a.y); r[2] = bf16r(a.z); r[3] = bf16r(a.w);
    r[4] = bf16r(b.x); r[5] = bf16r(b.y); r[6] = bf16r(b.z); r[7] = bf16r(b.w);
    return r;
}

// tanh via v_exp_f32; saturates correctly at +/-1 for |x| large
__device__ __forceinline__ float fast_tanh(float x) {
    float e = __expf(2.0f * x);
    return 1.0f - __fdividef(2.0f, e + 1.0f);
}

// ---------------------------------------------------------------------------
// Kernel 1: prep.
//   blocks [0,1024): W1T[u][d] = bf16(W1_w[d][u])   (B-operand needs K-contig)
//   blocks [1024,1088): qb[b][u] = query[b]@W2_w[:,u] + W2_b[u] + W1_b[u]
//   (V_b is dropped: softmax is shift-invariant)
// ---------------------------------------------------------------------------
__global__ void prep_kernel(const float* __restrict__ W1_w,
                            const float* __restrict__ W1_b,
                            const float* __restrict__ W2_w,
                            const float* __restrict__ W2_b,
                            const float* __restrict__ query,
                            unsigned short* __restrict__ W1T,
                            float* __restrict__ qb) {
    const int tid = threadIdx.x;
    if (blockIdx.x < 1024) {
        // transpose+convert W1 (1 MiB, L2-resident; strided reads absorbed)
        int idx = blockIdx.x * 256 + tid;        // 0 .. 262143
        int u = idx >> 9;                        // 0..511
        int d = idx & 511;
        W1T[u * D_DIM + d] = (unsigned short)bf16r(W1_w[d * U_DIM + u]);
    } else {
        int bid = blockIdx.x - 1024;             // 0..63
        int b = bid >> 1;
        int u = (bid & 1) * 256 + tid;
        float acc = W2_b[u] + W1_b[u];
        const float* q = query + b * D_DIM;
#pragma unroll 8
        for (int d = 0; d < D_DIM; ++d)
            acc += q[d] * W2_w[d * U_DIM + u];
        qb[b * U_DIM + u] = acc;
    }
}

// ---------------------------------------------------------------------------
// Kernel 2: fused score GEMM.
//   score[m] = sum_u V_w[u] * tanh( values[m,:]@W1[:,u] + qb[b,u] )
// Block = 256 threads (4 waves), 64 rows/block (16 rows/wave).
// A fragments (values rows, bf16) register-resident for full K=512: 64 VGPR.
// B (W1T) staged per 32-u chunk into LDS (row stride 1040 B -> 2-way bank
// aliasing only, which is free on CDNA4).
// mfma_f32_16x16x32_bf16:
//   A: lane holds A[m=lane&15][k=quad*8+j]; B: lane holds B[k=quad*8+j][n=lane&15]
//   D: col=lane&15 (u), row=quad*4+reg (m)
// ---------------------------------------------------------------------------
__global__ __launch_bounds__(256, 4) void score_kernel(
        const float* __restrict__ values,
        const unsigned short* __restrict__ W1T,
        const float* __restrict__ qb,
        const float* __restrict__ Vw,
        float* __restrict__ scores) {
    __shared__ unsigned char smem[32 * 1040];

    const int tid  = threadIdx.x;
    const int lane = tid & 63;
    const int w    = tid >> 6;       // wave id 0..3
    const int l15  = lane & 15;
    const int quad = lane >> 4;
    const int m0   = blockIdx.x * 64;
    const int b    = m0 >> 11;       // 2048 rows per batch; 64 | 2048

    // ---- load A fragments: 16 rows for this wave, full K ----
    const int row = m0 + w * 16 + l15;
    const float* vrow = values + (size_t)row * D_DIM + quad * 8;
    bf16x8 a_frag[16];
#pragma unroll
    for (int ks = 0; ks < 16; ++ks) {
        float4 f0 = *(const float4*)(vrow + ks * 32);
        float4 f1 = *(const float4*)(vrow + ks * 32 + 4);
        a_frag[ks] = pack_bf16x8(f0, f1);
    }

    float sacc[4] = {0.f, 0.f, 0.f, 0.f};

    for (int uc = 0; uc < 16; ++uc) {
        // ---- stage 32 rows of W1T (32 x 512 bf16 = 32 KiB) into LDS ----
        const uint4* src = (const uint4*)(W1T + (size_t)uc * 32 * D_DIM);
        __syncthreads();   // previous iteration's LDS reads must be done
#pragma unroll
        for (int i = 0; i < 8; ++i) {
            int idx = tid + i * 256;         // 0..2047 16-byte units
            int r = idx >> 6;                // lds row 0..31
            int c = idx & 63;                // unit within row
            *(uint4*)(&smem[r * 1040 + c * 16]) = src[r * 64 + c];
        }
        __syncthreads();

        // ---- two 16-u tiles, K-loop ----
        f32x4 acc0 = {0.f, 0.f, 0.f, 0.f};
        f32x4 acc1 = {0.f, 0.f, 0.f, 0.f};
        const unsigned char* bb0 = &smem[l15 * 1040 + quad * 16];
        const unsigned char* bb1 = &smem[(16 + l15) * 1040 + quad * 16];
#pragma unroll
        for (int ks = 0; ks < 16; ++ks) {
            bf16x8 b0 = *(const bf16x8*)(bb0 + ks * 64);
            bf16x8 b1 = *(const bf16x8*)(bb1 + ks * 64);
            acc0 = __builtin_amdgcn_mfma_f32_16x16x32_bf16(a_frag[ks], b0, acc0, 0, 0, 0);
            acc1 = __builtin_amdgcn_mfma_f32_16x16x32_bf16(a_frag[ks], b1, acc1, 0, 0, 0);
        }

        // ---- epilogue: tanh + V_w weighting, accumulate per-row partials ----
        const int u0 = uc * 32 + l15;
        const float qv0 = qb[b * U_DIM + u0];
        const float vw0 = Vw[u0];
        const float qv1 = qb[b * U_DIM + u0 + 16];
        const float vw1 = Vw[u0 + 16];
#pragma unroll
        for (int r = 0; r < 4; ++r) {
            sacc[r] += fast_tanh(acc0[r] + qv0) * vw0;
            sacc[r] += fast_tanh(acc1[r] + qv1) * vw1;
        }
    }

    // ---- reduce across the 16 lanes of each quad (the u dimension) ----
#pragma unroll
    for (int r = 0; r < 4; ++r) {
        float v = sacc[r];
        v += __shfl_xor(v, 1, 64);
        v += __shfl_xor(v, 2, 64);
        v += __shfl_xor(v, 4, 64);
        v += __shfl_xor(v, 8, 64);
        sacc[r] = v;
    }
    if (l15 == 0) {
#pragma unroll
        for (int r = 0; r < 4; ++r)
            scores[m0 + w * 16 + quad * 4 + r] = sacc[r];
    }
}

// ---------------------------------------------------------------------------
// Kernel 3: per-batch softmax over T=2048; writes attention weights to d_out
// and zeroes the context region (so kernel 4 can atomicAdd).
// ---------------------------------------------------------------------------
__global__ void softmax_kernel(const float* __restrict__ scores,
                               float* __restrict__ out) {
    const int b = blockIdx.x;
    const int tid = threadIdx.x;

    // zero context region for this batch
    out[b * D_DIM + tid] = 0.0f;
    out[b * D_DIM + 256 + tid] = 0.0f;

    float v[8];
    float mx = -1e30f;
#pragma unroll
    for (int i = 0; i < 8; ++i) {
        v[i] = scores[b * T_DIM + i * 256 + tid];
        mx = fmaxf(mx, v[i]);
    }
#pragma unroll
    for (int off = 1; off < 64; off <<= 1)
        mx = fmaxf(mx, __shfl_xor(mx, off, 64));
    __shared__ float redm[4];
    if ((tid & 63) == 0) redm[tid >> 6] = mx;
    __syncthreads();
    mx = fmaxf(fmaxf(redm[0], redm[1]), fmaxf(redm[2], redm[3]));

    float sum = 0.f;
#pragma unroll
    for (int i = 0; i < 8; ++i) {
        v[i] = __expf(v[i] - mx);
        sum += v[i];
    }
#pragma unroll
    for (int off = 1; off < 64; off <<= 1)
        sum += __shfl_xor(sum, off, 64);
    __shared__ float reds[4];
    if ((tid & 63) == 0) reds[tid >> 6] = sum;
    __syncthreads();
    sum = reds[0] + reds[1] + reds[2] + reds[3];

    const float inv = 1.0f / sum;
#pragma unroll
    for (int i = 0; i < 8; ++i)
        out[B_DIM * D_DIM + b * T_DIM + i * 256 + tid] = v[i] * inv;
}

// ---------------------------------------------------------------------------
// Kernel 4: context[b,d] = sum_t w[b,t] * values[b,t,d]
// grid (t-chunk=8, d-chunk=2, b=32); one atomicAdd per thread at the end.
// values is L3-warm from kernel 2 (128 MiB fits the 256 MiB Infinity Cache).
// ---------------------------------------------------------------------------
__global__ void context_kernel(const float* __restrict__ values,
                               const float* __restrict__ weights,
                               float* __restrict__ ctx) {
    __shared__ float sw[256];
    const int tc = blockIdx.x;   // 0..7  (256 t each)
    const int dc = blockIdx.y;   // 0..1  (256 d each)
    const int b  = blockIdx.z;   // 0..31
    const int tid = threadIdx.x;

    sw[tid] = weights[b * T_DIM + tc * 256 + tid];
    __syncthreads();

    const int d = dc * 256 + tid;
    const float* vbase = values + ((size_t)b * T_DIM + tc * 256) * D_DIM + d;
    float acc = 0.f;
#pragma unroll 8
    for (int i = 0; i < 256; ++i)
        acc += sw[i] * vbase[(size_t)i * D_DIM];
    atomicAdd(&ctx[b * D_DIM + d], acc);
}

// ---------------------------------------------------------------------------
extern "C" void kernel_launch(void* const* d_in, const int* in_sizes, int n_in,
                              void* d_out, int out_size, void* d_ws, size_t ws_size,
                              hipStream_t stream) {
    const float* values = (const float*)d_in[0];
    const float* query  = (const float*)d_in[1];
    const float* W1_w   = (const float*)d_in[2];
    const float* W1_b   = (const float*)d_in[3];
    const float* W2_w   = (const float*)d_in[4];
    const float* W2_b   = (const float*)d_in[5];
    const float* V_w    = (const float*)d_in[6];
    // V_b (d_in[7]) dropped: softmax is shift-invariant.

    float* out = (float*)d_out;

    // workspace layout
    unsigned char* ws = (unsigned char*)d_ws;
    unsigned short* W1T = (unsigned short*)(ws);                 // 512 KiB
    float* qb     = (float*)(ws + 524288);                       // 64 KiB
    float* scores = (float*)(ws + 524288 + 65536);               // 256 KiB

    prep_kernel<<<1088, 256, 0, stream>>>(W1_w, W1_b, W2_w, W2_b, query, W1T, qb);
    score_kernel<<<M_DIM / 64, 256, 0, stream>>>(values, W1T, qb, V_w, scores);
    softmax_kernel<<<B_DIM, 256, 0, stream>>>(scores, out);
    context_kernel<<<dim3(8, 2, B_DIM), 256, 0, stream>>>(values, out + B_DIM * D_DIM, out);
}

// Round 2
// 305.300 us; speedup vs baseline: 1.0834x; 1.0834x over previous
//
#include <hip/hip_runtime.h>
#include <hip/hip_bf16.h>

// Problem: Bahdanau attention. B=32, T=2048, D=512, U=512.
// d_in: values[B,T,D] f32, query[B,D] f32, W1_w[D,U], W1_b[U], W2_w[D,U],
//       W2_b[U], V_w[U,1], V_b[1]
// d_out: context[B,D] (16384 f32) then attention_weights[B,T,1] (65536 f32)

#define B_DIM 32
#define T_DIM 2048
#define D_DIM 512
#define U_DIM 512
#define M_DIM (B_DIM * T_DIM)   // 65536 rows

typedef short bf16x8 __attribute__((ext_vector_type(8)));
typedef float f32x4 __attribute__((ext_vector_type(4)));

// round-to-nearest-even f32 -> bf16
__device__ __forceinline__ short bf16r(float x) {
    unsigned u = __float_as_uint(x);
    u += 0x7fffu + ((u >> 16) & 1u);
    return (short)(u >> 16);
}

__device__ __forceinline__ bf16x8 pack_bf16x8(float4 a, float4 b) {
    bf16x8 r;
    r[0] = bf16r(a.x); r[1] = bf16r(a.y); r[2] = bf16r(a.z); r[3] = bf16r(a.w);
    r[4] = bf16r(b.x); r[5] = bf16r(b.y); r[6] = bf16r(b.z); r[7] = bf16r(b.w);
    return r;
}

__device__ __forceinline__ float fast_tanh(float x) {
    float e = __expf(2.0f * x);
    return 1.0f - __fdividef(2.0f, e + 1.0f);
}

// ---------------------------------------------------------------------------
// W1T swizzled slab layout (16-byte units of 8 bf16 along d):
//   unit (u, c) [c = d>>3] lives at unit-index (u>>5)*2048 + c*32 + (u&31)
// so that score staging lane idx (reading the slab CONTIGUOUSLY) writes LDS
// row (idx&31), unit (idx>>5): consecutive lanes hit consecutive padded rows
// -> 2 lanes per 4-bank group -> conflict-free. Global side stays contiguous.
// ---------------------------------------------------------------------------

// Kernel 1: prep.
//   blocks [0,128): W1T units (one thread = one 16B unit, coalesced both ways)
//   blocks [128,192): qb[b][u] = query[b]@W2_w[:,u] + W2_b[u] + W1_b[u]
__global__ void prep_kernel(const float* __restrict__ W1_w,
                            const float* __restrict__ W1_b,
                            const float* __restrict__ W2_w,
                            const float* __restrict__ W2_b,
                            const float* __restrict__ query,
                            unsigned short* __restrict__ W1T,
                            float* __restrict__ qb) {
    const int tid = threadIdx.x;
    if (blockIdx.x < 128) {
        int n = blockIdx.x * 256 + tid;   // unit id 0..32767
        int u = n & 511;
        int c = n >> 9;                   // 0..63
        bf16x8 pk;
#pragma unroll
        for (int j = 0; j < 8; ++j)
            pk[j] = bf16r(W1_w[(c * 8 + j) * U_DIM + u]);  // coalesced in u
        ((bf16x8*)W1T)[(u >> 5) * 2048 + c * 32 + (u & 31)] = pk;
    } else {
        int bid = blockIdx.x - 128;       // 0..63
        int b = bid >> 1;
        int u = (bid & 1) * 256 + tid;
        float acc = W2_b[u] + W1_b[u];
        const float* q = query + b * D_DIM;
#pragma unroll 8
        for (int d = 0; d < D_DIM; ++d)
            acc += q[d] * W2_w[d * U_DIM + u];
        qb[b * U_DIM + u] = acc;
    }
}

// ---------------------------------------------------------------------------
// Kernel 2: fused score GEMM.
//   score[m] = sum_u V_w[u] * tanh( values[m,:]@W1[:,u] + qb[b,u] )
// Block = 256 threads (4 waves), 64 rows/block (16 rows/wave).
// A fragments register-resident for full K=512 (64 regs/lane);
// __launch_bounds__(256,2) gives a 256-VGPR budget so they must NOT spill
// (v1 with (256,4) spilled: VGPR_Count=64, 44MB scratch writes).
// B staged per 32-u chunk into padded LDS rows (1040 B stride).
// ---------------------------------------------------------------------------
__global__ __launch_bounds__(256, 2) void score_kernel(
        const float* __restrict__ values,
        const unsigned short* __restrict__ W1T,
        const float* __restrict__ qb,
        const float* __restrict__ Vw,
        float* __restrict__ scores) {
    __shared__ unsigned char smem[32 * 1040];

    const int tid  = threadIdx.x;
    const int lane = tid & 63;
    const int w    = tid >> 6;       // wave id 0..3
    const int l15  = lane & 15;
    const int quad = lane >> 4;
    const int m0   = blockIdx.x * 64;
    const int b    = m0 >> 11;       // 2048 rows per batch; 64 | 2048

    // ---- load A fragments: 16 rows for this wave, full K ----
    const int row = m0 + w * 16 + l15;
    const float* vrow = values + (size_t)row * D_DIM + quad * 8;
    bf16x8 a_frag[16];
#pragma unroll
    for (int ks = 0; ks < 16; ++ks) {
        float4 f0 = *(const float4*)(vrow + ks * 32);
        float4 f1 = *(const float4*)(vrow + ks * 32 + 4);
        a_frag[ks] = pack_bf16x8(f0, f1);
    }

    float sacc[4] = {0.f, 0.f, 0.f, 0.f};

    for (int uc = 0; uc < 16; ++uc) {
        // ---- stage one 32-u slab (32 KiB, contiguous in swizzled layout) ----
        const bf16x8* src = (const bf16x8*)W1T + uc * 2048;
        __syncthreads();   // previous iteration's LDS reads must be done
#pragma unroll
        for (int i = 0; i < 8; ++i) {
            int idx = tid + i * 256;         // 0..2047 16-byte units
            int r = idx & 31;                // lds row (u within slab)
            int c = idx >> 5;                // unit within row (d chunk)
            *(bf16x8*)(&smem[r * 1040 + c * 16]) = src[idx];
        }
        __syncthreads();

        // ---- two 16-u tiles, K-loop ----
        f32x4 acc0 = {0.f, 0.f, 0.f, 0.f};
        f32x4 acc1 = {0.f, 0.f, 0.f, 0.f};
        const unsigned char* bb0 = &smem[l15 * 1040 + quad * 16];
        const unsigned char* bb1 = &smem[(16 + l15) * 1040 + quad * 16];
#pragma unroll
        for (int ks = 0; ks < 16; ++ks) {
            bf16x8 b0 = *(const bf16x8*)(bb0 + ks * 64);
            bf16x8 b1 = *(const bf16x8*)(bb1 + ks * 64);
            acc0 = __builtin_amdgcn_mfma_f32_16x16x32_bf16(a_frag[ks], b0, acc0, 0, 0, 0);
            acc1 = __builtin_amdgcn_mfma_f32_16x16x32_bf16(a_frag[ks], b1, acc1, 0, 0, 0);
        }

        // ---- epilogue: tanh + V_w weighting, accumulate per-row partials ----
        const int u0 = uc * 32 + l15;
        const float qv0 = qb[b * U_DIM + u0];
        const float vw0 = Vw[u0];
        const float qv1 = qb[b * U_DIM + u0 + 16];
        const float vw1 = Vw[u0 + 16];
#pragma unroll
        for (int r = 0; r < 4; ++r) {
            sacc[r] += fast_tanh(acc0[r] + qv0) * vw0;
            sacc[r] += fast_tanh(acc1[r] + qv1) * vw1;
        }
    }

    // ---- reduce across the 16 lanes of each quad (the u dimension) ----
#pragma unroll
    for (int r = 0; r < 4; ++r) {
        float v = sacc[r];
        v += __shfl_xor(v, 1, 64);
        v += __shfl_xor(v, 2, 64);
        v += __shfl_xor(v, 4, 64);
        v += __shfl_xor(v, 8, 64);
        sacc[r] = v;
    }
    if (l15 == 0) {
#pragma unroll
        for (int r = 0; r < 4; ++r)
            scores[m0 + w * 16 + quad * 4 + r] = sacc[r];
    }
}

// ---------------------------------------------------------------------------
// Kernel 3: per-batch softmax over T=2048; writes attention weights to d_out
// and zeroes the context region (so kernel 4 can atomicAdd).
// ---------------------------------------------------------------------------
__global__ void softmax_kernel(const float* __restrict__ scores,
                               float* __restrict__ out) {
    const int b = blockIdx.x;
    const int tid = threadIdx.x;

    out[b * D_DIM + tid] = 0.0f;
    out[b * D_DIM + 256 + tid] = 0.0f;

    float v[8];
    float mx = -1e30f;
#pragma unroll
    for (int i = 0; i < 8; ++i) {
        v[i] = scores[b * T_DIM + i * 256 + tid];
        mx = fmaxf(mx, v[i]);
    }
#pragma unroll
    for (int off = 1; off < 64; off <<= 1)
        mx = fmaxf(mx, __shfl_xor(mx, off, 64));
    __shared__ float redm[4];
    if ((tid & 63) == 0) redm[tid >> 6] = mx;
    __syncthreads();
    mx = fmaxf(fmaxf(redm[0], redm[1]), fmaxf(redm[2], redm[3]));

    float sum = 0.f;
#pragma unroll
    for (int i = 0; i < 8; ++i) {
        v[i] = __expf(v[i] - mx);
        sum += v[i];
    }
#pragma unroll
    for (int off = 1; off < 64; off <<= 1)
        sum += __shfl_xor(sum, off, 64);
    __shared__ float reds[4];
    if ((tid & 63) == 0) reds[tid >> 6] = sum;
    __syncthreads();
    sum = reds[0] + reds[1] + reds[2] + reds[3];

    const float inv = 1.0f / sum;
#pragma unroll
    for (int i = 0; i < 8; ++i)
        out[B_DIM * D_DIM + b * T_DIM + i * 256 + tid] = v[i] * inv;
}

// ---------------------------------------------------------------------------
// Kernel 4: context[b,d] = sum_t w[b,t] * values[b,t,d]
// values is L3-warm from kernel 2 (128 MiB fits the 256 MiB Infinity Cache).
// ---------------------------------------------------------------------------
__global__ void context_kernel(const float* __restrict__ values,
                               const float* __restrict__ weights,
                               float* __restrict__ ctx) {
    __shared__ float sw[256];
    const int tc = blockIdx.x;   // 0..7  (256 t each)
    const int dc = blockIdx.y;   // 0..1  (256 d each)
    const int b  = blockIdx.z;   // 0..31
    const int tid = threadIdx.x;

    sw[tid] = weights[b * T_DIM + tc * 256 + tid];
    __syncthreads();

    const int d = dc * 256 + tid;
    const float* vbase = values + ((size_t)b * T_DIM + tc * 256) * D_DIM + d;
    float acc = 0.f;
#pragma unroll 8
    for (int i = 0; i < 256; ++i)
        acc += sw[i] * vbase[(size_t)i * D_DIM];
    atomicAdd(&ctx[b * D_DIM + d], acc);
}

// ---------------------------------------------------------------------------
extern "C" void kernel_launch(void* const* d_in, const int* in_sizes, int n_in,
                              void* d_out, int out_size, void* d_ws, size_t ws_size,
                              hipStream_t stream) {
    const float* values = (const float*)d_in[0];
    const float* query  = (const float*)d_in[1];
    const float* W1_w   = (const float*)d_in[2];
    const float* W1_b   = (const float*)d_in[3];
    const float* W2_w   = (const float*)d_in[4];
    const float* W2_b   = (const float*)d_in[5];
    const float* V_w    = (const float*)d_in[6];
    // V_b (d_in[7]) dropped: softmax is shift-invariant.

    float* out = (float*)d_out;

    unsigned char* ws = (unsigned char*)d_ws;
    unsigned short* W1T = (unsigned short*)(ws);                 // 512 KiB
    float* qb     = (float*)(ws + 524288);                       // 64 KiB
    float* scores = (float*)(ws + 524288 + 65536);               // 256 KiB

    prep_kernel<<<192, 256, 0, stream>>>(W1_w, W1_b, W2_w, W2_b, query, W1T, qb);
    score_kernel<<<M_DIM / 64, 256, 0, stream>>>(values, W1T, qb, V_w, scores);
    softmax_kernel<<<B_DIM, 256, 0, stream>>>(scores, out);
    context_kernel<<<dim3(8, 2, B_DIM), 256, 0, stream>>>(values, out + B_DIM * D_DIM, out);
}

// Round 3
// 287.121 us; speedup vs baseline: 1.1520x; 1.0633x over previous
//
#include <hip/hip_runtime.h>
#include <hip/hip_bf16.h>
#include <stdint.h>

// Problem: Bahdanau attention. B=32, T=2048, D=512, U=512.
// d_out: context[B,D] (16384 f32) then attention_weights[B,T,1] (65536 f32)

#define B_DIM 32
#define T_DIM 2048
#define D_DIM 512
#define U_DIM 512
#define M_DIM (B_DIM * T_DIM)   // 65536 rows

typedef short bf16x8 __attribute__((ext_vector_type(8)));
typedef float f32x4 __attribute__((ext_vector_type(4)));

// round-to-nearest-even f32 -> bf16
__device__ __forceinline__ short bf16r(float x) {
    unsigned u = __float_as_uint(x);
    u += 0x7fffu + ((u >> 16) & 1u);
    return (short)(u >> 16);
}

__device__ __forceinline__ bf16x8 pack_bf16x8(float4 a, float4 b) {
    bf16x8 r;
    r[0] = bf16r(a.x); r[1] = bf16r(a.y); r[2] = bf16r(a.z); r[3] = bf16r(a.w);
    r[4] = bf16r(b.x); r[5] = bf16r(b.y); r[6] = bf16r(b.z); r[7] = bf16r(b.w);
    return r;
}

__device__ __forceinline__ float fast_tanh(float x) {
    float e = __expf(2.0f * x);
    return 1.0f - __fdividef(2.0f, e + 1.0f);
}

// async global->LDS, 16B per lane. LDS dest is wave-uniform base + lane*16.
// CK-style address-space cast idiom (generic LDS ptr low 32 bits = LDS offset).
__device__ __forceinline__ void g2lds16(const void* g, void* lds) {
    auto gp = reinterpret_cast<const __attribute__((address_space(1))) unsigned int*>(
        reinterpret_cast<uintptr_t>(g));
    auto lp = reinterpret_cast<__attribute__((address_space(3))) unsigned int*>(
        (unsigned int)(uintptr_t)lds);
    __builtin_amdgcn_global_load_lds(gp, lp, 16, 0, 0);
}

// ---------------------------------------------------------------------------
// W1T swizzled linear layout in 16-byte units (8 bf16 along d):
//   slab s = u>>5 (32 u per slab); within slab, unit index = c*32 + (u&31),
//   c = d>>3. A slab (2048 units = 32 KiB) is CONTIGUOUS, so score staging is
//   a pure linear copy -> global_load_lds works and LDS layout == global.
// ---------------------------------------------------------------------------

// Kernel 1: prep.
//   blocks [0,128): W1T units (one thread = one 16B unit, coalesced both ways)
//   blocks [128,384): qb[b][u] = query[b]@W2_w[:,u] + W2_b[u] + W1_b[u]
//     (b, u-group of 64) per block; 4 d-quarters per thread + LDS reduce.
//   V_b dropped: softmax is shift-invariant.
__global__ void prep_kernel(const float* __restrict__ W1_w,
                            const float* __restrict__ W1_b,
                            const float* __restrict__ W2_w,
                            const float* __restrict__ W2_b,
                            const float* __restrict__ query,
                            unsigned short* __restrict__ W1T,
                            float* __restrict__ qb) {
    __shared__ float red[256];
    const int tid = threadIdx.x;
    if (blockIdx.x < 128) {
        int n = blockIdx.x * 256 + tid;   // unit id 0..32767
        int u = n & 511;
        int c = n >> 9;                   // 0..63
        bf16x8 pk;
#pragma unroll
        for (int j = 0; j < 8; ++j)
            pk[j] = bf16r(W1_w[(c * 8 + j) * U_DIM + u]);  // coalesced in u
        ((bf16x8*)W1T)[(u >> 5) * 2048 + c * 32 + (u & 31)] = pk;
    } else {
        int bid = blockIdx.x - 128;       // 0..255
        int b  = bid >> 3;
        int ug = bid & 7;
        int u  = ug * 64 + (tid & 63);
        int dq = tid >> 6;                // 0..3 (128 d each)
        const float* q  = query + b * D_DIM + dq * 128;
        const float* w2 = W2_w + (size_t)(dq * 128) * U_DIM + u;
        float acc = 0.f;
#pragma unroll 8
        for (int d = 0; d < 128; ++d)
            acc += q[d] * w2[(size_t)d * U_DIM];
        red[tid] = acc;
        __syncthreads();
        if (tid < 64) {
            float s = red[tid] + red[tid + 64] + red[tid + 128] + red[tid + 192]
                    + W2_b[u] + W1_b[u];
            qb[b * U_DIM + u] = s;
        }
    }
}

// ---------------------------------------------------------------------------
// Kernel 2: fused score GEMM.
//   score[m] = sum_u V_w[u] * tanh( values[m,:]@W1[:,u] + qb[b,u] )
// 512 blocks x 256 threads (4 waves). 128 rows/block; wave = 32 rows =
// 2 M-tiles, A register-resident for full K=512 (128 VGPRs/lane) -> each
// LDS B read feeds 2 MFMAs. B staged per 32-u slab via global_load_lds
// width=16 (no VGPR round trip). Linear slab layout: lane (quad,l15) reads
// B-frag at quad*512 + l15*16 (+256 hi tile) + ks*2048 -> contiguous 256 B
// per quad = conflict-free ds_read_b128.
// mfma_f32_16x16x32_bf16: A[m=l15][k=quad*8+j]; D: col=l15(u), row=quad*4+r.
// ---------------------------------------------------------------------------
__global__ __launch_bounds__(256, 2) void score_kernel(
        const float* __restrict__ values,
        const unsigned short* __restrict__ W1T,
        const float* __restrict__ qb,
        const float* __restrict__ Vw,
        float* __restrict__ scores) {
    __shared__ __align__(16) unsigned char smem[32 * 1024];

    const int tid  = threadIdx.x;
    const int lane = tid & 63;
    const int w    = tid >> 6;       // wave 0..3
    const int l15  = lane & 15;
    const int quad = lane >> 4;
    const int m0   = blockIdx.x * 128;
    const int b    = m0 >> 11;       // 128 | 2048

    // ---- issue async staging of slab 0 (overlaps A loads below) ----
#pragma unroll
    for (int i = 0; i < 8; ++i) {
        int unit = i * 256 + w * 64 + lane;
        g2lds16(W1T + (size_t)unit * 8, smem + (i * 256 + w * 64) * 16);
    }

    // ---- A fragments: 2 tiles x 16 rows, full K ----
    const int r0 = m0 + w * 32 + l15;
    const float* vrow0 = values + (size_t)r0 * D_DIM + quad * 8;
    const float* vrow1 = vrow0 + 16 * D_DIM;
    bf16x8 a0[16], a1[16];
#pragma unroll
    for (int ks = 0; ks < 16; ++ks) {
        float4 f0 = *(const float4*)(vrow0 + ks * 32);
        float4 f1 = *(const float4*)(vrow0 + ks * 32 + 4);
        a0[ks] = pack_bf16x8(f0, f1);
        float4 g0 = *(const float4*)(vrow1 + ks * 32);
        float4 g1 = *(const float4*)(vrow1 + ks * 32 + 4);
        a1[ks] = pack_bf16x8(g0, g1);
    }

    float sacc0[4] = {0.f, 0.f, 0.f, 0.f};
    float sacc1[4] = {0.f, 0.f, 0.f, 0.f};

    for (int uc = 0; uc < 16; ++uc) {
        __syncthreads();   // staging of slab uc complete (barrier drains vmcnt)

        f32x4 acc0l = {0,0,0,0}, acc0h = {0,0,0,0};
        f32x4 acc1l = {0,0,0,0}, acc1h = {0,0,0,0};
        const unsigned char* bbase = smem + quad * 512 + l15 * 16;
#pragma unroll
        for (int ks = 0; ks < 16; ++ks) {
            bf16x8 blo = *(const bf16x8*)(bbase + ks * 2048);
            bf16x8 bhi = *(const bf16x8*)(bbase + ks * 2048 + 256);
            acc0l = __builtin_amdgcn_mfma_f32_16x16x32_bf16(a0[ks], blo, acc0l, 0, 0, 0);
            acc0h = __builtin_amdgcn_mfma_f32_16x16x32_bf16(a0[ks], bhi, acc0h, 0, 0, 0);
            acc1l = __builtin_amdgcn_mfma_f32_16x16x32_bf16(a1[ks], blo, acc1l, 0, 0, 0);
            acc1h = __builtin_amdgcn_mfma_f32_16x16x32_bf16(a1[ks], bhi, acc1h, 0, 0, 0);
        }

        // ---- epilogue: tanh + V_w weighting ----
        const int u0 = uc * 32 + l15;
        const float qv0 = qb[b * U_DIM + u0];
        const float vw0 = Vw[u0];
        const float qv1 = qb[b * U_DIM + u0 + 16];
        const float vw1 = Vw[u0 + 16];
#pragma unroll
        for (int r = 0; r < 4; ++r) {
            sacc0[r] += fast_tanh(acc0l[r] + qv0) * vw0 + fast_tanh(acc0h[r] + qv1) * vw1;
            sacc1[r] += fast_tanh(acc1l[r] + qv0) * vw0 + fast_tanh(acc1h[r] + qv1) * vw1;
        }

        if (uc < 15) {
            __syncthreads();   // all waves done reading smem
            const unsigned short* src = W1T + (size_t)(uc + 1) * 32 * D_DIM;
#pragma unroll
            for (int i = 0; i < 8; ++i) {
                int unit = i * 256 + w * 64 + lane;
                g2lds16(src + (size_t)unit * 8, smem + (i * 256 + w * 64) * 16);
            }
        }
    }

    // ---- reduce across the 16 lanes of each quad (u dimension) ----
#pragma unroll
    for (int r = 0; r < 4; ++r) {
        float v0 = sacc0[r], v1 = sacc1[r];
        v0 += __shfl_xor(v0, 1, 64); v1 += __shfl_xor(v1, 1, 64);
        v0 += __shfl_xor(v0, 2, 64); v1 += __shfl_xor(v1, 2, 64);
        v0 += __shfl_xor(v0, 4, 64); v1 += __shfl_xor(v1, 4, 64);
        v0 += __shfl_xor(v0, 8, 64); v1 += __shfl_xor(v1, 8, 64);
        sacc0[r] = v0; sacc1[r] = v1;
    }
    if (l15 == 0) {
        const int rowbase = m0 + w * 32 + quad * 4;
#pragma unroll
        for (int r = 0; r < 4; ++r) {
            scores[rowbase + r]      = sacc0[r];
            scores[rowbase + 16 + r] = sacc1[r];
        }
    }
}

// ---------------------------------------------------------------------------
// Kernel 3: per-batch softmax over T=2048; writes attention weights to d_out
// and zeroes the context region (so kernel 4 can atomicAdd).
// ---------------------------------------------------------------------------
__global__ void softmax_kernel(const float* __restrict__ scores,
                               float* __restrict__ out) {
    const int b = blockIdx.x;
    const int tid = threadIdx.x;

    out[b * D_DIM + tid] = 0.0f;
    out[b * D_DIM + 256 + tid] = 0.0f;

    float v[8];
    float mx = -1e30f;
#pragma unroll
    for (int i = 0; i < 8; ++i) {
        v[i] = scores[b * T_DIM + i * 256 + tid];
        mx = fmaxf(mx, v[i]);
    }
#pragma unroll
    for (int off = 1; off < 64; off <<= 1)
        mx = fmaxf(mx, __shfl_xor(mx, off, 64));
    __shared__ float redm[4];
    if ((tid & 63) == 0) redm[tid >> 6] = mx;
    __syncthreads();
    mx = fmaxf(fmaxf(redm[0], redm[1]), fmaxf(redm[2], redm[3]));

    float sum = 0.f;
#pragma unroll
    for (int i = 0; i < 8; ++i) {
        v[i] = __expf(v[i] - mx);
        sum += v[i];
    }
#pragma unroll
    for (int off = 1; off < 64; off <<= 1)
        sum += __shfl_xor(sum, off, 64);
    __shared__ float reds[4];
    if ((tid & 63) == 0) reds[tid >> 6] = sum;
    __syncthreads();
    sum = reds[0] + reds[1] + reds[2] + reds[3];

    const float inv = 1.0f / sum;
#pragma unroll
    for (int i = 0; i < 8; ++i)
        out[B_DIM * D_DIM + b * T_DIM + i * 256 + tid] = v[i] * inv;
}

// ---------------------------------------------------------------------------
// Kernel 4: context[b,d] = sum_t w[b,t] * values[b,t,d]
// grid (16 t-chunks, 32 b), 128 threads = one float4 d-quad per thread.
// values is L3-warm from kernel 2. One atomicAdd x4 per thread.
// ---------------------------------------------------------------------------
__global__ void context_kernel(const float* __restrict__ values,
                               const float* __restrict__ weights,
                               float* __restrict__ ctx) {
    __shared__ float sw[128];
    const int tc = blockIdx.x;   // 0..15 (128 t each)
    const int b  = blockIdx.y;
    const int tid = threadIdx.x; // 0..127 -> d-quad

    sw[tid] = weights[b * T_DIM + tc * 128 + tid];
    __syncthreads();

    const float4* vbase = (const float4*)(values + ((size_t)b * T_DIM + tc * 128) * D_DIM) + tid;
    float4 acc = {0.f, 0.f, 0.f, 0.f};
#pragma unroll 8
    for (int i = 0; i < 128; ++i) {
        float wv = sw[i];
        float4 v = vbase[(size_t)i * 128];
        acc.x += wv * v.x; acc.y += wv * v.y;
        acc.z += wv * v.z; acc.w += wv * v.w;
    }
    float* dst = ctx + b * D_DIM + tid * 4;
    atomicAdd(dst + 0, acc.x);
    atomicAdd(dst + 1, acc.y);
    atomicAdd(dst + 2, acc.z);
    atomicAdd(dst + 3, acc.w);
}

// ---------------------------------------------------------------------------
extern "C" void kernel_launch(void* const* d_in, const int* in_sizes, int n_in,
                              void* d_out, int out_size, void* d_ws, size_t ws_size,
                              hipStream_t stream) {
    const float* values = (const float*)d_in[0];
    const float* query  = (const float*)d_in[1];
    const float* W1_w   = (const float*)d_in[2];
    const float* W1_b   = (const float*)d_in[3];
    const float* W2_w   = (const float*)d_in[4];
    const float* W2_b   = (const float*)d_in[5];
    const float* V_w    = (const float*)d_in[6];
    // V_b (d_in[7]) dropped: softmax is shift-invariant.

    float* out = (float*)d_out;

    unsigned char* ws = (unsigned char*)d_ws;
    unsigned short* W1T = (unsigned short*)(ws);                 // 512 KiB
    float* qb     = (float*)(ws + 524288);                       // 64 KiB
    float* scores = (float*)(ws + 524288 + 65536);               // 256 KiB

    prep_kernel<<<384, 256, 0, stream>>>(W1_w, W1_b, W2_w, W2_b, query, W1T, qb);
    score_kernel<<<M_DIM / 128, 256, 0, stream>>>(values, W1T, qb, V_w, scores);
    softmax_kernel<<<B_DIM, 256, 0, stream>>>(scores, out);
    context_kernel<<<dim3(16, B_DIM), 128, 0, stream>>>(values, out + B_DIM * D_DIM, out);
}